// Round 17
// baseline (124.857 us; speedup 1.0000x reference)
//
#include <hip/hip_runtime.h>
#include <stdint.h>

// OSTL spiking-LIF forward.
// R17: DISPATCH-COUNT experiment: 4 kernels -> 2, all numerics bit-identical
//   to R13 (106.9us best). Theory: residual ~30us is inter-dispatch gap
//   (~8us each), not kernel time — two dead theories (f64 chain R13, gemm
//   occupancy R14/R16) point at the decomposition, and rocprof.md's ~10us
//   launch-overhead gotcha fits the residual exactly.
//   - gemm_splitk: byte-identical to R13 (BM128/BN128/BK32, unroll 8).
//   - scan_direct: wave-per-column; lane l loads the 8 k-chunk partials for
//     its timesteps directly (reduce8's exact pairwise tree, in-register),
//     R13's exact f32 readlane chain, direct scattered spike stores
//     (L2 write-combines 1024 blocks -> 2MB HBM). yb/bits round-trips gone.

#define T_STEPS 512
#define IN_SZ   1024
#define OUT_SZ  1024

#define BM 128
#define BN 128
#define BK 32
#define KSPLIT 8
#define KCHUNK (IN_SZ / KSPLIT)    // 128
#define NITER  (KCHUNK / BK)       // 4

typedef __attribute__((address_space(1))) const void gvoid;
typedef __attribute__((address_space(3))) void lvoid;

__global__ __launch_bounds__(256) void ostl_gemm_splitk(const float* __restrict__ X,
                                                        const float* __restrict__ W,
                                                        float* __restrict__ P) {
    __shared__ float As[2][BK][BM];     // A transposed [k][m]
    __shared__ float Bs[2][BK * BN];    // linear [k][n]; global_load_lds dest

    const int tid = threadIdx.x;
    const int tx = tid & 15;            // output cols tx*4..+3 and +64..+67
    const int ty = tid >> 4;            // output rows ty*8..+7
    const int n0 = blockIdx.x * BN;
    const int m0 = blockIdx.y * BM;
    const int kc = blockIdx.z;
    const int kb = kc * KCHUNK;

    const int am = tid >> 1;            // A row staged by this thread (0..127)
    const int ak = (tid & 1) * 16;      // A k-offset (0 or 16)
    const int wv = tid >> 6;            // wave 0..3
    const int ln = tid & 63;            // lane

    const float* Arow = X + (size_t)(m0 + am) * IN_SZ + kb + ak;

    float4 areg[4];

    // ---- prologue: tile 0 -> buffer 0 ----
    #pragma unroll
    for (int q = 0; q < 4; ++q)
        areg[q] = *reinterpret_cast<const float4*>(Arow + q * 4);
    #pragma unroll
    for (int j = 0; j < 4; ++j) {
        const int i = wv * 4 + j;
        const float* src = W + (size_t)(kb + 2 * i + (ln >> 5)) * OUT_SZ + n0 + (ln & 31) * 4;
        __builtin_amdgcn_global_load_lds((gvoid*)src, (lvoid*)&Bs[0][i * 256], 16, 0, 0);
    }
    {
        float t[16];
        #pragma unroll
        for (int q = 0; q < 4; ++q) *reinterpret_cast<float4*>(&t[q * 4]) = areg[q];
        #pragma unroll
        for (int c = 0; c < 16; ++c) As[0][ak + c][am] = t[c];
    }
    __syncthreads();

    float acc[8][8];
    #pragma unroll
    for (int r = 0; r < 8; ++r)
        #pragma unroll
        for (int c = 0; c < 8; ++c) acc[r][c] = 0.f;

    #pragma unroll 1
    for (int it = 0; it < NITER; ++it) {
        const int cur = it & 1;
        const int nxt = cur ^ 1;

        if (it < NITER - 1) {
            const int kbase = kb + (it + 1) * BK;
            #pragma unroll
            for (int j = 0; j < 4; ++j) {
                const int i = wv * 4 + j;
                const float* src = W + (size_t)(kbase + 2 * i + (ln >> 5)) * OUT_SZ + n0 + (ln & 31) * 4;
                __builtin_amdgcn_global_load_lds((gvoid*)src, (lvoid*)&Bs[nxt][i * 256], 16, 0, 0);
            }
            #pragma unroll
            for (int q = 0; q < 4; ++q)
                areg[q] = *reinterpret_cast<const float4*>(Arow + (it + 1) * BK + q * 4);
        }

        // 64 MACs per 64 LDS bytes per k-step (1 B/MAC); same fmaf order
        // per output element as R6..R13 (bitwise-identical partials).
        #pragma unroll 8
        for (int k = 0; k < BK; ++k) {
            const float4 a0 = *reinterpret_cast<const float4*>(&As[cur][k][ty * 8]);
            const float4 a1 = *reinterpret_cast<const float4*>(&As[cur][k][ty * 8 + 4]);
            const float4 b0 = *reinterpret_cast<const float4*>(&Bs[cur][k * BN + tx * 4]);
            const float4 b1 = *reinterpret_cast<const float4*>(&Bs[cur][k * BN + tx * 4 + 64]);
            const float av[8] = {a0.x, a0.y, a0.z, a0.w, a1.x, a1.y, a1.z, a1.w};
            const float bv[8] = {b0.x, b0.y, b0.z, b0.w, b1.x, b1.y, b1.z, b1.w};
            #pragma unroll
            for (int r = 0; r < 8; ++r)
                #pragma unroll
                for (int c = 0; c < 8; ++c)
                    acc[r][c] = fmaf(av[r], bv[c], acc[r][c]);
        }

        if (it < NITER - 1) {
            float t[16];
            #pragma unroll
            for (int q = 0; q < 4; ++q) *reinterpret_cast<float4*>(&t[q * 4]) = areg[q];
            #pragma unroll
            for (int c = 0; c < 16; ++c) As[nxt][ak + c][am] = t[c];
            __syncthreads();
        }
    }

    float* Pb = P + (size_t)kc * T_STEPS * OUT_SZ + (size_t)(m0 + ty * 8) * OUT_SZ + n0;
    #pragma unroll
    for (int r = 0; r < 8; ++r) {
        *reinterpret_cast<float4*>(&Pb[(size_t)r * OUT_SZ + tx * 4]) =
            make_float4(acc[r][0], acc[r][1], acc[r][2], acc[r][3]);
        *reinterpret_cast<float4*>(&Pb[(size_t)r * OUT_SZ + tx * 4 + 64]) =
            make_float4(acc[r][4], acc[r][5], acc[r][6], acc[r][7]);
    }
}

// Wave-per-column scan with in-register reduce (reduce8's exact pairwise
// tree) and direct spike stores. Lane l owns timesteps t = q*64+l.
__global__ __launch_bounds__(64) void ostl_scan_direct(const float* __restrict__ u0,
                                                       const float* __restrict__ P,
                                                       float* __restrict__ Sout,
                                                       float* __restrict__ u_final) {
    const int j = blockIdx.x;       // column
    const int l = threadIdx.x;      // lane
    const size_t CS = (size_t)T_STEPS * OUT_SZ;   // chunk stride in P

    const float sig_f = (float)0.8807970779778823;

    float u = u0[j];

    // q=0: load 8 chunk partials, reduce with the exact reduce8 tree.
    float ycur;
    {
        float raw[8];
        #pragma unroll
        for (int c = 0; c < 8; ++c)
            raw[c] = P[c * CS + (size_t)l * OUT_SZ + j];
        const float t0 = raw[0] + raw[1], t1 = raw[2] + raw[3];
        const float t2 = raw[4] + raw[5], t3 = raw[6] + raw[7];
        ycur = (t0 + t1) + (t2 + t3);
    }

    #pragma unroll 1
    for (int q = 0; q < 8; ++q) {
        float rawn[8];
        if (q < 7) {                                   // prefetch next q-block
            #pragma unroll
            for (int c = 0; c < 8; ++c)
                rawn[c] = P[c * CS + (size_t)((q + 1) * 64 + l) * OUT_SZ + j];
        }
        float spk = 0.f;
        #pragma unroll
        for (int i = 0; i < 64; ++i) {
            const float yv = __int_as_float(
                __builtin_amdgcn_readlane(__float_as_int(ycur), i));
            const float un = fmaf(sig_f, u, yv);       // R13's exact chain
            const float us = un - 1.0f;
            const bool  sp = un > 1.0f;
            if (i == l) spk = sp ? 1.0f : 0.0f;        // off-chain
            u = sp ? us : un;
        }
        Sout[(size_t)(q * 64 + l) * OUT_SZ + j] = spk; // scattered; L2 combines
        if (q < 7) {
            const float t0 = rawn[0] + rawn[1], t1 = rawn[2] + rawn[3];
            const float t2 = rawn[4] + rawn[5], t3 = rawn[6] + rawn[7];
            ycur = (t0 + t1) + (t2 + t3);
        }
    }
    if (l == 0) u_final[j] = u;
}

extern "C" void kernel_launch(void* const* d_in, const int* in_sizes, int n_in,
                              void* d_out, int out_size, void* d_ws, size_t ws_size,
                              hipStream_t stream) {
    const float* x_seq  = (const float*)d_in[0];   // [512,1024]
    const float* kernel = (const float*)d_in[1];   // [1024,1024]
    const float* u0     = (const float*)d_in[2];   // [1024]
    // d_in[3] = E0: unused in the primal path.

    float* out      = (float*)d_out;
    float* spikes   = out;                               // [512,1024]
    float* u_final  = out + (size_t)T_STEPS * OUT_SZ;    // [1024]

    float* partials = (float*)d_ws;                      // 8 x [512,1024] = 16 MB

    dim3 ggrid(OUT_SZ / BN, T_STEPS / BM, KSPLIT);       // (8, 4, 8) = 256 blocks
    ostl_gemm_splitk<<<ggrid, dim3(256), 0, stream>>>(x_seq, kernel, partials);

    ostl_scan_direct<<<dim3(OUT_SZ), dim3(64), 0, stream>>>(u0, partials, spikes, u_final);
}